// Round 8
// baseline (3123.339 us; speedup 1.0000x reference)
//
#include <hip/hip_runtime.h>

#define N_NODES 100000
#define N_EDGES 3200000
#define N_GRAPHS 1000
#define NLAYER 4
#define NB 391           // coarse buckets: dst>>8, 391*256 = 100096 >= N_NODES
#define CAP 8960         // fixed slot cap per bucket (mean 8184, sd 90: +8.6 sigma)
#define EPB 4096         // edges per scatter chunk
#define NCHUNK 782       // 782*4096 >= N_EDGES
#define NBLK 1024        // persistent grid: 4 blocks/CU x 256 CUs (guaranteed resident)
#define NTHREADS 256
#define NWAVE 4096       // NBLK*4
#define N_TILES 6250     // N_NODES/16 (exact)
#define N_GRP 25000      // N_NODES/4 (exact)

typedef __attribute__((ext_vector_type(8))) short bf16x8;
typedef __attribute__((ext_vector_type(4))) float f32x4;

static __device__ __forceinline__ unsigned f2bf(float f) {
  unsigned u = __float_as_uint(f);
  return (u + 0x7fffu + ((u >> 16) & 1u)) >> 16;
}
static __device__ __forceinline__ float bf2f_lo(unsigned u) {
  return __uint_as_float(u << 16);
}
static __device__ __forceinline__ float bf2f_hi(unsigned u) {
  return __uint_as_float(u & 0xffff0000u);
}

// ---------------------------------------------------------------------------
// Two-level grid barrier. bar layout (128B-padded lines):
//   leaf i (i=0..31): bar[i*32]   root: bar[32*32]   gen: bar[33*32]
// All 1024 blocks call this at every phase boundary; no block ever exits
// early (no returns in mega), so arrival is guaranteed. Residency is
// guaranteed by __launch_bounds__(256,4): 4 blocks/CU x 256 CU = 1024.
static __device__ __forceinline__ void gbar(int* bar, int bid) {
  __syncthreads();
  if (threadIdx.x == 0) {
    __threadfence();  // release block's prior writes (flush XCD L2)
    int gen = __hip_atomic_load(bar + 33 * 32, __ATOMIC_RELAXED,
                                __HIP_MEMORY_SCOPE_AGENT);
    int* leaf = bar + (bid & 31) * 32;
    int old = __hip_atomic_fetch_add(leaf, 1, __ATOMIC_ACQ_REL,
                                     __HIP_MEMORY_SCOPE_AGENT);
    if (old == 31) {  // last of this leaf's 32 blocks
      __hip_atomic_store(leaf, 0, __ATOMIC_RELAXED, __HIP_MEMORY_SCOPE_AGENT);
      int rold = __hip_atomic_fetch_add(bar + 32 * 32, 1, __ATOMIC_ACQ_REL,
                                        __HIP_MEMORY_SCOPE_AGENT);
      if (rold == 31) {  // last leaf
        __hip_atomic_store(bar + 32 * 32, 0, __ATOMIC_RELAXED,
                           __HIP_MEMORY_SCOPE_AGENT);
        __hip_atomic_fetch_add(bar + 33 * 32, 1, __ATOMIC_RELEASE,
                               __HIP_MEMORY_SCOPE_AGENT);
      }
    }
    while (__hip_atomic_load(bar + 33 * 32, __ATOMIC_ACQUIRE,
                             __HIP_MEMORY_SCOPE_AGENT) == gen)
      __builtin_amdgcn_s_sleep(2);
    __threadfence();  // acquire: invalidate caches before next phase reads
  }
  __syncthreads();
}

__global__ __launch_bounds__(256) void zero_bar_kernel(int* __restrict__ bar)
{
  int i = threadIdx.x;
  for (; i < 34 * 32; i += 256) bar[i] = 0;
}

// ---------------------------------------------------------------------------
union SMem {
  struct {  // scatter phase: 31.1 KB
    unsigned hist[NB];
    int dif[NB];
    unsigned stage_w[EPB];
    unsigned char stage_d[EPB];
    unsigned short bid_[EPB];
    int wpart[4];
  } sc;
  struct {  // sort phase: 21.0 KB
    unsigned hist[256];
    float dws[256];
    unsigned cur[256];
    int wpart[4];
    unsigned short perm[CAP];
  } so;
};

// ---------------------------------------------------------------------------
// THE kernel: embed+wswz+init -> scatter -> sort -> 4x(matvec -> agg) -> head,
// separated by grid barriers. 1024 blocks x 256 threads, all resident.
__global__ __launch_bounds__(256, 4) void mega_kernel(
    const float* __restrict__ x, const int* __restrict__ ei,
    const float* __restrict__ ea, const int* __restrict__ batch,
    const float* __restrict__ emb_w, const float* __restrict__ emb_b,
    const float* __restrict__ cw1, const float* __restrict__ cb1,
    const float* __restrict__ cw2, const float* __restrict__ cw3,
    const float* __restrict__ cb3, const float* __restrict__ l1w,
    const float* __restrict__ l1b, const float* __restrict__ l2w,
    const float* __restrict__ l2b, float* __restrict__ out,
    float* __restrict__ h, unsigned short* __restrict__ h_bf,
    unsigned short* __restrict__ a_bf, unsigned short* __restrict__ cc_bf,
    unsigned* __restrict__ csr, int* __restrict__ row_off,
    unsigned short* __restrict__ deg16, float* __restrict__ degw,
    int* __restrict__ gcur, unsigned* __restrict__ wswz,
    unsigned* __restrict__ tmp_w, unsigned char* __restrict__ tmp_d,
    int* __restrict__ bar)
{
  __shared__ SMem sm;
  int bid = blockIdx.x;
  int tid = threadIdx.x;
  int lane = tid & 63;
  int wv = tid >> 6;
  int gw = bid * 4 + wv;  // global wave id, 0..4095

  // ---- phase 0: embed (grid-stride) + gcur init + wswz ----
  for (int t = bid * NTHREADS + tid; t < N_NODES * 64; t += NBLK * NTHREADS) {
    int c = t & 63, v = t >> 6;
    float4 xv = ((const float4*)x)[v];
    float acc = emb_b[c];
    acc = fmaf(xv.x, emb_w[0 * 64 + c], acc);
    acc = fmaf(xv.y, emb_w[1 * 64 + c], acc);
    acc = fmaf(xv.z, emb_w[2 * 64 + c], acc);
    acc = fmaf(xv.w, emb_w[3 * 64 + c], acc);
    h_bf[t] = (unsigned short)f2bf(acc);
  }
  if (bid == NBLK - 1) {
    for (int i = tid; i < NB; i += NTHREADS) gcur[i] = i * CAP;
  }
  if (bid < NLAYER) {  // weight swizzle, one layer per block
    int l = bid;
    const float* w1 = cw1 + l * 4096;
    const float* w2 = cw2 + l * 4096;
    const float* w3 = cw3 + l * 4096;
    unsigned* outp = wswz + l * 6144;
    int n = tid & 63;
    int gofs = tid >> 6;
    for (int it = 0; it < 24; ++it) {
      int g = it * 4 + gofs;
      int m = g >> 5;
      int k = (g & 31) * 2;
      const float* W = (m == 0) ? w2 : (m == 1) ? w3 : w1;
      unsigned lo = f2bf(W[k * 64 + n]);
      unsigned hi = f2bf(W[(k + 1) * 64 + n]);
      int c = k >> 5;
      int kk = k & 31;
      int ln = ((kk >> 3) << 4) | (n & 15);
      int j2 = (kk & 7) >> 1;
      int t4 = n >> 4;
      outp[(((m * 2 + c) * 4 + t4) << 8) | (ln << 2) | j2] = lo | (hi << 16);
    }
  }
  gbar(bar, bid);

  // ---- phase 1: staged scatter into fixed-cap bucket slots ----
  for (int ch = bid; ch < NCHUNK; ch += NBLK) {
    int base = ch * EPB;
    for (int i = tid; i < NB; i += NTHREADS) sm.sc.hist[i] = 0;
    __syncthreads();

    int dreg[16];
#pragma unroll
    for (int i = 0; i < 16; ++i) {
      int e = base + i * 256 + tid;
      dreg[i] = -1;
      if (e < N_EDGES) {
        int d = ei[N_EDGES + e];
        dreg[i] = d;
        atomicAdd(&sm.sc.hist[((unsigned)d) >> 8], 1u);
      }
    }
    __syncthreads();

    // exclusive scan over NB buckets (2/thread) + global range claim
    int b0i = tid * 2, b1i = tid * 2 + 1;
    int c0 = (b0i < NB) ? (int)sm.sc.hist[b0i] : 0;
    int c1 = (b1i < NB) ? (int)sm.sc.hist[b1i] : 0;
    int tsum = c0 + c1;
    int s = tsum;
#pragma unroll
    for (int off = 1; off < 64; off <<= 1) {
      int y = __shfl_up(s, off);
      if (lane >= off) s += y;
    }
    if (lane == 63) sm.sc.wpart[wv] = s;
    __syncthreads();
    int wo = 0;
    for (int ww = 0; ww < wv; ++ww) wo += sm.sc.wpart[ww];
    int excl = wo + (s - tsum);
    if (b0i < NB) {
      int gb = c0 ? atomicAdd(&gcur[b0i], c0) : 0;
      sm.sc.dif[b0i] = gb - excl;
      sm.sc.hist[b0i] = (unsigned)excl;
    }
    if (b1i < NB) {
      int gb = c1 ? atomicAdd(&gcur[b1i], c1) : 0;
      sm.sc.dif[b1i] = gb - (excl + c0);
      sm.sc.hist[b1i] = (unsigned)(excl + c0);
    }
    __syncthreads();

    // stage in bucket-sorted order
#pragma unroll
    for (int i = 0; i < 16; ++i) {
      int e = base + i * 256 + tid;
      int d = dreg[i];
      if (d >= 0) {
        unsigned bkt = ((unsigned)d) >> 8;
        unsigned lp = atomicAdd(&sm.sc.hist[bkt], 1u);
        unsigned q15 = (unsigned)(ea[e] * 32768.0f);  // ew in [0,1)
        sm.sc.stage_w[lp] = ((unsigned)ei[e]) | (q15 << 17);
        sm.sc.stage_d[lp] = (unsigned char)(d & 255);
        sm.sc.bid_[lp] = (unsigned short)bkt;
      }
    }
    __syncthreads();

    // coalesced flush (slotted positions)
    int nE = min(EPB, N_EDGES - base);
    for (int i = tid; i < nE; i += NTHREADS) {
      int g = sm.sc.dif[sm.sc.bid_[i]] + i;
      tmp_w[g] = sm.sc.stage_w[i];
      tmp_d[g] = sm.sc.stage_d[i];
    }
    __syncthreads();
  }
  gbar(bar, bid);

  // ---- phase 2: per-bucket 256-bin counting sort -> csr, row_off, degw ----
  for (int j = bid; j < NB; j += NBLK) {
    int b0 = j * CAP;
    int nE = min(gcur[j] - b0, CAP);
    sm.so.hist[tid] = 0;
    sm.so.dws[tid] = 0.f;
    __syncthreads();
    for (int i = tid; i < nE; i += NTHREADS) {
      unsigned d = tmp_d[b0 + i];
      unsigned wrd = tmp_w[b0 + i];
      atomicAdd(&sm.so.hist[d], 1u);
      atomicAdd(&sm.so.dws[d], (float)(wrd >> 17) * (1.0f / 32768.0f));
    }
    __syncthreads();
    int v = (int)sm.so.hist[tid];
    int s = v;
#pragma unroll
    for (int off = 1; off < 64; off <<= 1) {
      int y = __shfl_up(s, off);
      if (lane >= off) s += y;
    }
    if (lane == 63) sm.so.wpart[wv] = s;
    __syncthreads();
    int wo = 0;
    for (int ww = 0; ww < wv; ++ww) wo += sm.so.wpart[ww];
    int excl = wo + s - v;
    sm.so.cur[tid] = (unsigned)excl;
    int vnode = (j << 8) + tid;
    if (vnode < N_NODES) {
      row_off[vnode] = b0 + excl;
      deg16[vnode] = (unsigned short)v;
      degw[vnode] = sm.so.dws[tid];
    }
    __syncthreads();
    for (int i = tid; i < nE; i += NTHREADS) {
      unsigned p = atomicAdd(&sm.so.cur[tmp_d[b0 + i]], 1u);
      sm.so.perm[p] = (unsigned short)i;
    }
    __syncthreads();
    for (int q = tid; q < nE; q += NTHREADS)
      csr[b0 + q] = tmp_w[b0 + (int)sm.so.perm[q]];
    __syncthreads();
  }
  gbar(bar, bid);

  // ---- phases 3..10: 4 x (matvec -> barrier -> agg -> barrier) ----
  int quad = lane >> 4;
  int col = lane & 15;
  int sg = lane >> 4;
  int li = lane & 15;
  int lsel = (lane & 48) << 2;

  for (int l = 0; l < NLAYER; ++l) {
    const unsigned* wz = wswz + l * 6144;
    const float* b1 = cb1 + l * 64;
    const float* b3 = cb3 + l * 64;

    // matvec: one 16-node tile per wave, grid-stride
    for (int tile = gw; tile < N_TILES; tile += NWAVE) {
      int nb = tile * 16;
      int arow = nb + col;  // always < N_NODES (6250*16 == 100000)
      const bf16x8* ap = (const bf16x8*)(h_bf + (size_t)arow * 64 + quad * 8);
      bf16x8 af0 = ap[0];
      bf16x8 af1 = ap[4];
      float dwr[4];
#pragma unroll
      for (int r = 0; r < 4; ++r) dwr[r] = degw[nb + quad * 4 + r];

#pragma unroll
      for (int t = 0; t < 4; ++t) {
        const bf16x8* b20 = (const bf16x8*)&wz[((0 * 4 + t) << 8) + lane * 4];
        const bf16x8* b21 = (const bf16x8*)&wz[((1 * 4 + t) << 8) + lane * 4];
        const bf16x8* b30 = (const bf16x8*)&wz[((2 * 4 + t) << 8) + lane * 4];
        const bf16x8* b31 = (const bf16x8*)&wz[((3 * 4 + t) << 8) + lane * 4];
        const bf16x8* b10 = (const bf16x8*)&wz[((4 * 4 + t) << 8) + lane * 4];
        const bf16x8* b11 = (const bf16x8*)&wz[((5 * 4 + t) << 8) + lane * 4];

        f32x4 z = {0.f, 0.f, 0.f, 0.f};
        f32x4 acc2 = __builtin_amdgcn_mfma_f32_16x16x32_bf16(af0, *b20, z, 0, 0, 0);
        acc2 = __builtin_amdgcn_mfma_f32_16x16x32_bf16(af1, *b21, acc2, 0, 0, 0);
        f32x4 cc;
#pragma unroll
        for (int r = 0; r < 4; ++r) cc[r] = -dwr[r] * acc2[r];
        cc = __builtin_amdgcn_mfma_f32_16x16x32_bf16(af0, *b30, cc, 0, 0, 0);
        cc = __builtin_amdgcn_mfma_f32_16x16x32_bf16(af1, *b31, cc, 0, 0, 0);
        float bb3 = b3[t * 16 + col];
#pragma unroll
        for (int r = 0; r < 4; ++r) {
          int row = nb + quad * 4 + r;
          cc_bf[(size_t)row * 64 + t * 16 + col] = (unsigned short)f2bf(cc[r] + bb3);
        }
        float bb1 = b1[t * 16 + col];
        f32x4 a1 = {bb1, bb1, bb1, bb1};
        a1 = __builtin_amdgcn_mfma_f32_16x16x32_bf16(af0, *b10, a1, 0, 0, 0);
        a1 = __builtin_amdgcn_mfma_f32_16x16x32_bf16(af1, *b11, a1, 0, 0, 0);
#pragma unroll
        for (int r = 0; r < 4; ++r) {
          int row = nb + quad * 4 + r;
          a_bf[(size_t)row * 64 + t * 16 + col] = (unsigned short)f2bf(a1[r]);
        }
      }
    }
    gbar(bar, bid);

    // agg: 4 consecutive nodes per wave, grid-stride
    const uint2* a2 = (const uint2*)a_bf;
    const uint2* cc2 = (const uint2*)cc_bf;
    int write_h = (l == NLAYER - 1);
    for (int grp = gw; grp < N_GRP; grp += NWAVE) {
      int v = grp * 4 + sg;  // always < N_NODES (25000*4 == 100000)
      int base = row_off[v];
      int ecnt = (int)deg16[v];
      int emax = ecnt;
      emax = max(emax, __shfl_xor(emax, 16));
      emax = max(emax, __shfl_xor(emax, 32));

      uint2 cu = cc2[(size_t)v * 16 + li];
      float4 acc;
      acc.x = bf2f_lo(cu.x);
      acc.y = bf2f_hi(cu.x);
      acc.z = bf2f_lo(cu.y);
      acc.w = bf2f_hi(cu.y);
      const uint2* ap = a2 + li;

      int full = emax & ~15;
      int c0 = 0;
      for (; c0 < full; c0 += 16) {
        int idx = c0 + li;
        int er = (idx < ecnt) ? (int)csr[base + idx] : 0;  // pad: src 0, w 0
#pragma unroll
        for (int j = 0; j < 16; ++j) {
          unsigned r = (unsigned)__builtin_amdgcn_ds_bpermute(lsel | (j << 2), er);
          int s = (int)(r & 0x1FFFFu);
          float w = (float)(r >> 17) * (1.0f / 32768.0f);
          uint2 u = ap[(size_t)s * 16];
          acc.x = fmaf(w, bf2f_lo(u.x), acc.x);
          acc.y = fmaf(w, bf2f_hi(u.x), acc.y);
          acc.z = fmaf(w, bf2f_lo(u.y), acc.z);
          acc.w = fmaf(w, bf2f_hi(u.y), acc.w);
        }
      }
      int rem = emax - full;
      if (rem > 0) {
        int idx = c0 + li;
        int er = (idx < ecnt) ? (int)csr[base + idx] : 0;
        for (int j = 0; j < rem; ++j) {
          unsigned r = (unsigned)__builtin_amdgcn_ds_bpermute(lsel | (j << 2), er);
          int s = (int)(r & 0x1FFFFu);
          float w = (float)(r >> 17) * (1.0f / 32768.0f);
          uint2 u = ap[(size_t)s * 16];
          acc.x = fmaf(w, bf2f_lo(u.x), acc.x);
          acc.y = fmaf(w, bf2f_hi(u.x), acc.y);
          acc.z = fmaf(w, bf2f_lo(u.y), acc.z);
          acc.w = fmaf(w, bf2f_hi(u.y), acc.w);
        }
      }
      acc.x = fmaxf(acc.x, 0.f);
      acc.y = fmaxf(acc.y, 0.f);
      acc.z = fmaxf(acc.z, 0.f);
      acc.w = fmaxf(acc.w, 0.f);
      if (write_h) ((float4*)h)[(size_t)v * 16 + li] = acc;
      uint2 p;
      p.x = f2bf(acc.x) | (f2bf(acc.y) << 16);
      p.y = f2bf(acc.z) | (f2bf(acc.w) << 16);
      ((uint2*)h_bf)[(size_t)v * 16 + li] = p;
    }
    gbar(bar, bid);
  }

  // ---- phase 11: head (mean-pool + lin1+relu + lin2), one wave per graph ----
  for (int g = gw; g < N_GRAPHS; g += NWAVE) {
    int lo = 0, hi = N_NODES;
    while (lo < hi) { int mid = (lo + hi) >> 1; if (batch[mid] < g) lo = mid + 1; else hi = mid; }
    int start = lo;
    hi = N_NODES;
    while (lo < hi) { int mid = (lo + hi) >> 1; if (batch[mid] < g + 1) lo = mid + 1; else hi = mid; }
    int end = lo;

    float sum = 0.f;
    for (int v = start; v < end; ++v) sum += h[(size_t)v * 64 + lane];
    float cntf = (float)(end - start);
    float gx = sum / fmaxf(cntf, 1.f);

    float acc = l1b[lane];
    for (int k = 0; k < 64; ++k) {
      float gxk = __shfl(gx, k);
      acc = fmaf(gxk, l1w[k * 64 + lane], acc);
    }
    float t = fmaxf(acc, 0.f);
    float p0 = t * l2w[lane * 3 + 0];
    float p1 = t * l2w[lane * 3 + 1];
    float p2 = t * l2w[lane * 3 + 2];
    for (int off = 32; off > 0; off >>= 1) {
      p0 += __shfl_down(p0, off);
      p1 += __shfl_down(p1, off);
      p2 += __shfl_down(p2, off);
    }
    if (lane == 0) {
      out[g * 3 + 0] = p0 + l2b[0];
      out[g * 3 + 1] = p1 + l2b[1];
      out[g * 3 + 2] = p2 + l2b[2];
    }
  }
}

// ---------------------------------------------------------------------------
extern "C" void kernel_launch(void* const* d_in, const int* in_sizes, int n_in,
                              void* d_out, int out_size, void* d_ws, size_t ws_size,
                              hipStream_t stream)
{
  (void)in_sizes; (void)n_in; (void)out_size; (void)ws_size;
  const float* x     = (const float*)d_in[0];
  const int*   ei    = (const int*)d_in[1];
  const float* ea    = (const float*)d_in[2];
  const int*   batch = (const int*)d_in[3];
  const float* emb_w = (const float*)d_in[4];
  const float* emb_b = (const float*)d_in[5];
  const float* cw1   = (const float*)d_in[6];
  const float* cb1   = (const float*)d_in[7];
  const float* cw2   = (const float*)d_in[8];
  const float* cw3   = (const float*)d_in[9];
  const float* cb3   = (const float*)d_in[10];
  const float* l1w   = (const float*)d_in[11];
  const float* l1b   = (const float*)d_in[12];
  const float* l2w   = (const float*)d_in[13];
  const float* l2b   = (const float*)d_in[14];
  float* out = (float*)d_out;

  char* wsb = (char*)d_ws;
  size_t off = 0;
  auto alloc = [&](size_t bytes) {
    char* p = wsb + off;
    off = (off + bytes + 255) & ~(size_t)255;
    return p;
  };
  float* h       = (float*)alloc(sizeof(float) * (size_t)N_NODES * 64);    // 25.6 MB
  unsigned short* h_bf = (unsigned short*)alloc(sizeof(short) * (size_t)N_NODES * 64);
  unsigned short* a_bf = (unsigned short*)alloc(sizeof(short) * (size_t)N_NODES * 64);
  unsigned short* cc_bf = (unsigned short*)alloc(sizeof(short) * (size_t)N_NODES * 64);
  unsigned* csr  = (unsigned*)alloc(sizeof(unsigned) * (size_t)NB * CAP);  // 14.0 MB slotted
  int*   row_off = (int*)alloc(sizeof(int) * N_NODES);
  unsigned short* deg16 = (unsigned short*)alloc(sizeof(short) * N_NODES);
  float* degw    = (float*)alloc(sizeof(float) * N_NODES);
  int*   gcur    = (int*)alloc(sizeof(int) * NB);
  unsigned* wswz = (unsigned*)alloc(sizeof(unsigned) * NLAYER * 6144);  // 96 KB
  int*   bar     = (int*)alloc(sizeof(int) * 34 * 32);
  // tmp_w (14.0 MB) + tmp_d (3.5 MB) alias h: h fp32 is only written by the
  // LAST agg phase, long after the sort phase consumed tmp (barriers order it).
  unsigned* tmp_w = (unsigned*)h;
  unsigned char* tmp_d = (unsigned char*)h + sizeof(unsigned) * (size_t)NB * CAP;

  zero_bar_kernel<<<1, 256, 0, stream>>>(bar);
  mega_kernel<<<NBLK, NTHREADS, 0, stream>>>(
      x, ei, ea, batch, emb_w, emb_b, cw1, cb1, cw2, cw3, cb3,
      l1w, l1b, l2w, l2b, out,
      h, h_bf, a_bf, cc_bf, csr, row_off, deg16, degw, gcur, wswz,
      tmp_w, tmp_d, bar);
}

// Round 9
// 1185.240 us; speedup vs baseline: 2.6352x; 2.6352x over previous
//
#include <hip/hip_runtime.h>

#define N_NODES 100000
#define N_EDGES 3200000
#define N_GRAPHS 1000
#define NLAYER 4
#define NB 391           // coarse buckets: dst>>8, 391*256 = 100096 >= N_NODES
#define CAP 8960         // fixed slot cap per bucket (mean 8184, sd 90: +8.6 sigma)
#define EPB 4096         // edges per scatter chunk
#define NCHUNK 782       // 782*4096 >= N_EDGES
#define NBLK 1024        // persistent grid: 4 blocks/CU x 256 CUs (guaranteed resident)
#define NTHREADS 256
#define NWAVE 4096       // NBLK*4
#define N_TILES 6250     // N_NODES/16 (exact)
#define N_GRP 25000      // N_NODES/4 (exact)

typedef __attribute__((ext_vector_type(8))) short bf16x8;
typedef __attribute__((ext_vector_type(4))) float f32x4;

static __device__ __forceinline__ unsigned f2bf(float f) {
  unsigned u = __float_as_uint(f);
  return (u + 0x7fffu + ((u >> 16) & 1u)) >> 16;
}
static __device__ __forceinline__ float bf2f_lo(unsigned u) {
  return __uint_as_float(u << 16);
}
static __device__ __forceinline__ float bf2f_hi(unsigned u) {
  return __uint_as_float(u & 0xffff0000u);
}

// ---------------------------------------------------------------------------
// Two-level grid barrier. bar layout (128B-padded lines):
//   leaf i (i=0..31): bar[i*32]   root: bar[32*32]   gen: bar[33*32]
// All 1024 blocks call this at every phase boundary; no block ever exits
// early (no returns in mega), so arrival is guaranteed. Residency is
// guaranteed by __launch_bounds__(256,4): 4 blocks/CU x 256 CU = 1024.
//
// CRITICAL (round-8 lesson): the poll MUST be RELAXED. An ACQUIRE load at
// agent scope emits a cache-invalidate per iteration — spinning blocks
// continuously nuke their CU's L1 while co-resident blocks still work,
// collapsing every phase to raw-latency (3081 us vs ~450 expected).
// Ordering is provided by one release fence before arrival and ONE acquire
// fence after the generation bump is observed.
static __device__ __forceinline__ void gbar(int* bar, int bid) {
  __syncthreads();
  if (threadIdx.x == 0) {
    __threadfence();  // release block's prior writes
    int gen = __hip_atomic_load(bar + 33 * 32, __ATOMIC_RELAXED,
                                __HIP_MEMORY_SCOPE_AGENT);
    int* leaf = bar + (bid & 31) * 32;
    int old = __hip_atomic_fetch_add(leaf, 1, __ATOMIC_RELAXED,
                                     __HIP_MEMORY_SCOPE_AGENT);
    if (old == 31) {  // last of this leaf's 32 blocks
      __hip_atomic_store(leaf, 0, __ATOMIC_RELAXED, __HIP_MEMORY_SCOPE_AGENT);
      int rold = __hip_atomic_fetch_add(bar + 32 * 32, 1, __ATOMIC_RELAXED,
                                        __HIP_MEMORY_SCOPE_AGENT);
      if (rold == 31) {  // last leaf
        __hip_atomic_store(bar + 32 * 32, 0, __ATOMIC_RELAXED,
                           __HIP_MEMORY_SCOPE_AGENT);
        __hip_atomic_fetch_add(bar + 33 * 32, 1, __ATOMIC_RELAXED,
                               __HIP_MEMORY_SCOPE_AGENT);
      }
    }
    // relaxed poll: NO per-iteration cache invalidate
    while (__hip_atomic_load(bar + 33 * 32, __ATOMIC_RELAXED,
                             __HIP_MEMORY_SCOPE_AGENT) == gen)
      __builtin_amdgcn_s_sleep(16);
    __threadfence();  // single acquire: invalidate once, after release seen
  }
  __syncthreads();
}

__global__ __launch_bounds__(256) void zero_bar_kernel(int* __restrict__ bar)
{
  int i = threadIdx.x;
  for (; i < 34 * 32; i += 256) bar[i] = 0;
}

// ---------------------------------------------------------------------------
union SMem {
  struct {  // scatter phase: 31.1 KB
    unsigned hist[NB];
    int dif[NB];
    unsigned stage_w[EPB];
    unsigned char stage_d[EPB];
    unsigned short bid_[EPB];
    int wpart[4];
  } sc;
  struct {  // sort phase: 21.0 KB
    unsigned hist[256];
    float dws[256];
    unsigned cur[256];
    int wpart[4];
    unsigned short perm[CAP];
  } so;
};

// ---------------------------------------------------------------------------
// THE kernel: embed+wswz+init -> scatter -> sort -> 4x(matvec -> agg) -> head,
// separated by grid barriers. 1024 blocks x 256 threads, all resident.
__global__ __launch_bounds__(256, 4) void mega_kernel(
    const float* __restrict__ x, const int* __restrict__ ei,
    const float* __restrict__ ea, const int* __restrict__ batch,
    const float* __restrict__ emb_w, const float* __restrict__ emb_b,
    const float* __restrict__ cw1, const float* __restrict__ cb1,
    const float* __restrict__ cw2, const float* __restrict__ cw3,
    const float* __restrict__ cb3, const float* __restrict__ l1w,
    const float* __restrict__ l1b, const float* __restrict__ l2w,
    const float* __restrict__ l2b, float* __restrict__ out,
    float* __restrict__ h, unsigned short* __restrict__ h_bf,
    unsigned short* __restrict__ a_bf, unsigned short* __restrict__ cc_bf,
    unsigned* __restrict__ csr, int* __restrict__ row_off,
    unsigned short* __restrict__ deg16, float* __restrict__ degw,
    int* __restrict__ gcur, unsigned* __restrict__ wswz,
    unsigned* __restrict__ tmp_w, unsigned char* __restrict__ tmp_d,
    int* __restrict__ bar)
{
  __shared__ SMem sm;
  int bid = blockIdx.x;
  int tid = threadIdx.x;
  int lane = tid & 63;
  int wv = tid >> 6;
  int gw = bid * 4 + wv;  // global wave id, 0..4095

  // ---- phase 0: embed (grid-stride) + gcur init + wswz ----
  for (int t = bid * NTHREADS + tid; t < N_NODES * 64; t += NBLK * NTHREADS) {
    int c = t & 63, v = t >> 6;
    float4 xv = ((const float4*)x)[v];
    float acc = emb_b[c];
    acc = fmaf(xv.x, emb_w[0 * 64 + c], acc);
    acc = fmaf(xv.y, emb_w[1 * 64 + c], acc);
    acc = fmaf(xv.z, emb_w[2 * 64 + c], acc);
    acc = fmaf(xv.w, emb_w[3 * 64 + c], acc);
    h_bf[t] = (unsigned short)f2bf(acc);
  }
  if (bid == NBLK - 1) {
    for (int i = tid; i < NB; i += NTHREADS) gcur[i] = i * CAP;
  }
  if (bid < NLAYER) {  // weight swizzle, one layer per block
    int l = bid;
    const float* w1 = cw1 + l * 4096;
    const float* w2 = cw2 + l * 4096;
    const float* w3 = cw3 + l * 4096;
    unsigned* outp = wswz + l * 6144;
    int n = tid & 63;
    int gofs = tid >> 6;
    for (int it = 0; it < 24; ++it) {
      int g = it * 4 + gofs;
      int m = g >> 5;
      int k = (g & 31) * 2;
      const float* W = (m == 0) ? w2 : (m == 1) ? w3 : w1;
      unsigned lo = f2bf(W[k * 64 + n]);
      unsigned hi = f2bf(W[(k + 1) * 64 + n]);
      int c = k >> 5;
      int kk = k & 31;
      int ln = ((kk >> 3) << 4) | (n & 15);
      int j2 = (kk & 7) >> 1;
      int t4 = n >> 4;
      outp[(((m * 2 + c) * 4 + t4) << 8) | (ln << 2) | j2] = lo | (hi << 16);
    }
  }
  gbar(bar, bid);

  // ---- phase 1: staged scatter into fixed-cap bucket slots ----
  for (int ch = bid; ch < NCHUNK; ch += NBLK) {
    int base = ch * EPB;
    for (int i = tid; i < NB; i += NTHREADS) sm.sc.hist[i] = 0;
    __syncthreads();

    int dreg[16];
#pragma unroll
    for (int i = 0; i < 16; ++i) {
      int e = base + i * 256 + tid;
      dreg[i] = -1;
      if (e < N_EDGES) {
        int d = ei[N_EDGES + e];
        dreg[i] = d;
        atomicAdd(&sm.sc.hist[((unsigned)d) >> 8], 1u);
      }
    }
    __syncthreads();

    // exclusive scan over NB buckets (2/thread) + global range claim
    int b0i = tid * 2, b1i = tid * 2 + 1;
    int c0 = (b0i < NB) ? (int)sm.sc.hist[b0i] : 0;
    int c1 = (b1i < NB) ? (int)sm.sc.hist[b1i] : 0;
    int tsum = c0 + c1;
    int s = tsum;
#pragma unroll
    for (int off = 1; off < 64; off <<= 1) {
      int y = __shfl_up(s, off);
      if (lane >= off) s += y;
    }
    if (lane == 63) sm.sc.wpart[wv] = s;
    __syncthreads();
    int wo = 0;
    for (int ww = 0; ww < wv; ++ww) wo += sm.sc.wpart[ww];
    int excl = wo + (s - tsum);
    if (b0i < NB) {
      int gb = c0 ? atomicAdd(&gcur[b0i], c0) : 0;
      sm.sc.dif[b0i] = gb - excl;
      sm.sc.hist[b0i] = (unsigned)excl;
    }
    if (b1i < NB) {
      int gb = c1 ? atomicAdd(&gcur[b1i], c1) : 0;
      sm.sc.dif[b1i] = gb - (excl + c0);
      sm.sc.hist[b1i] = (unsigned)(excl + c0);
    }
    __syncthreads();

    // stage in bucket-sorted order
#pragma unroll
    for (int i = 0; i < 16; ++i) {
      int e = base + i * 256 + tid;
      int d = dreg[i];
      if (d >= 0) {
        unsigned bkt = ((unsigned)d) >> 8;
        unsigned lp = atomicAdd(&sm.sc.hist[bkt], 1u);
        unsigned q15 = (unsigned)(ea[e] * 32768.0f);  // ew in [0,1)
        sm.sc.stage_w[lp] = ((unsigned)ei[e]) | (q15 << 17);
        sm.sc.stage_d[lp] = (unsigned char)(d & 255);
        sm.sc.bid_[lp] = (unsigned short)bkt;
      }
    }
    __syncthreads();

    // coalesced flush (slotted positions)
    int nE = min(EPB, N_EDGES - base);
    for (int i = tid; i < nE; i += NTHREADS) {
      int g = sm.sc.dif[sm.sc.bid_[i]] + i;
      tmp_w[g] = sm.sc.stage_w[i];
      tmp_d[g] = sm.sc.stage_d[i];
    }
    __syncthreads();
  }
  gbar(bar, bid);

  // ---- phase 2: per-bucket 256-bin counting sort -> csr, row_off, degw ----
  for (int j = bid; j < NB; j += NBLK) {
    int b0 = j * CAP;
    int nE = min(gcur[j] - b0, CAP);
    sm.so.hist[tid] = 0;
    sm.so.dws[tid] = 0.f;
    __syncthreads();
    for (int i = tid; i < nE; i += NTHREADS) {
      unsigned d = tmp_d[b0 + i];
      unsigned wrd = tmp_w[b0 + i];
      atomicAdd(&sm.so.hist[d], 1u);
      atomicAdd(&sm.so.dws[d], (float)(wrd >> 17) * (1.0f / 32768.0f));
    }
    __syncthreads();
    int v = (int)sm.so.hist[tid];
    int s = v;
#pragma unroll
    for (int off = 1; off < 64; off <<= 1) {
      int y = __shfl_up(s, off);
      if (lane >= off) s += y;
    }
    if (lane == 63) sm.so.wpart[wv] = s;
    __syncthreads();
    int wo = 0;
    for (int ww = 0; ww < wv; ++ww) wo += sm.so.wpart[ww];
    int excl = wo + s - v;
    sm.so.cur[tid] = (unsigned)excl;
    int vnode = (j << 8) + tid;
    if (vnode < N_NODES) {
      row_off[vnode] = b0 + excl;
      deg16[vnode] = (unsigned short)v;
      degw[vnode] = sm.so.dws[tid];
    }
    __syncthreads();
    for (int i = tid; i < nE; i += NTHREADS) {
      unsigned p = atomicAdd(&sm.so.cur[tmp_d[b0 + i]], 1u);
      sm.so.perm[p] = (unsigned short)i;
    }
    __syncthreads();
    for (int q = tid; q < nE; q += NTHREADS)
      csr[b0 + q] = tmp_w[b0 + (int)sm.so.perm[q]];
    __syncthreads();
  }
  gbar(bar, bid);

  // ---- phases 3..10: 4 x (matvec -> barrier -> agg -> barrier) ----
  int quad = lane >> 4;
  int col = lane & 15;
  int sg = lane >> 4;
  int li = lane & 15;
  int lsel = (lane & 48) << 2;

  for (int l = 0; l < NLAYER; ++l) {
    const unsigned* wz = wswz + l * 6144;
    const float* b1 = cb1 + l * 64;
    const float* b3 = cb3 + l * 64;

    // matvec: one 16-node tile per wave, grid-stride
    for (int tile = gw; tile < N_TILES; tile += NWAVE) {
      int nb = tile * 16;
      int arow = nb + col;  // always < N_NODES (6250*16 == 100000)
      const bf16x8* ap = (const bf16x8*)(h_bf + (size_t)arow * 64 + quad * 8);
      bf16x8 af0 = ap[0];
      bf16x8 af1 = ap[4];
      float dwr[4];
#pragma unroll
      for (int r = 0; r < 4; ++r) dwr[r] = degw[nb + quad * 4 + r];

#pragma unroll
      for (int t = 0; t < 4; ++t) {
        const bf16x8* b20 = (const bf16x8*)&wz[((0 * 4 + t) << 8) + lane * 4];
        const bf16x8* b21 = (const bf16x8*)&wz[((1 * 4 + t) << 8) + lane * 4];
        const bf16x8* b30 = (const bf16x8*)&wz[((2 * 4 + t) << 8) + lane * 4];
        const bf16x8* b31 = (const bf16x8*)&wz[((3 * 4 + t) << 8) + lane * 4];
        const bf16x8* b10 = (const bf16x8*)&wz[((4 * 4 + t) << 8) + lane * 4];
        const bf16x8* b11 = (const bf16x8*)&wz[((5 * 4 + t) << 8) + lane * 4];

        f32x4 z = {0.f, 0.f, 0.f, 0.f};
        f32x4 acc2 = __builtin_amdgcn_mfma_f32_16x16x32_bf16(af0, *b20, z, 0, 0, 0);
        acc2 = __builtin_amdgcn_mfma_f32_16x16x32_bf16(af1, *b21, acc2, 0, 0, 0);
        f32x4 cc;
#pragma unroll
        for (int r = 0; r < 4; ++r) cc[r] = -dwr[r] * acc2[r];
        cc = __builtin_amdgcn_mfma_f32_16x16x32_bf16(af0, *b30, cc, 0, 0, 0);
        cc = __builtin_amdgcn_mfma_f32_16x16x32_bf16(af1, *b31, cc, 0, 0, 0);
        float bb3 = b3[t * 16 + col];
#pragma unroll
        for (int r = 0; r < 4; ++r) {
          int row = nb + quad * 4 + r;
          cc_bf[(size_t)row * 64 + t * 16 + col] = (unsigned short)f2bf(cc[r] + bb3);
        }
        float bb1 = b1[t * 16 + col];
        f32x4 a1 = {bb1, bb1, bb1, bb1};
        a1 = __builtin_amdgcn_mfma_f32_16x16x32_bf16(af0, *b10, a1, 0, 0, 0);
        a1 = __builtin_amdgcn_mfma_f32_16x16x32_bf16(af1, *b11, a1, 0, 0, 0);
#pragma unroll
        for (int r = 0; r < 4; ++r) {
          int row = nb + quad * 4 + r;
          a_bf[(size_t)row * 64 + t * 16 + col] = (unsigned short)f2bf(a1[r]);
        }
      }
    }
    gbar(bar, bid);

    // agg: 4 consecutive nodes per wave, grid-stride
    const uint2* a2 = (const uint2*)a_bf;
    const uint2* cc2 = (const uint2*)cc_bf;
    int write_h = (l == NLAYER - 1);
    for (int grp = gw; grp < N_GRP; grp += NWAVE) {
      int v = grp * 4 + sg;  // always < N_NODES (25000*4 == 100000)
      int base = row_off[v];
      int ecnt = (int)deg16[v];
      int emax = ecnt;
      emax = max(emax, __shfl_xor(emax, 16));
      emax = max(emax, __shfl_xor(emax, 32));

      uint2 cu = cc2[(size_t)v * 16 + li];
      float4 acc;
      acc.x = bf2f_lo(cu.x);
      acc.y = bf2f_hi(cu.x);
      acc.z = bf2f_lo(cu.y);
      acc.w = bf2f_hi(cu.y);
      const uint2* ap = a2 + li;

      int full = emax & ~15;
      int c0 = 0;
      for (; c0 < full; c0 += 16) {
        int idx = c0 + li;
        int er = (idx < ecnt) ? (int)csr[base + idx] : 0;  // pad: src 0, w 0
#pragma unroll
        for (int j = 0; j < 16; ++j) {
          unsigned r = (unsigned)__builtin_amdgcn_ds_bpermute(lsel | (j << 2), er);
          int s = (int)(r & 0x1FFFFu);
          float w = (float)(r >> 17) * (1.0f / 32768.0f);
          uint2 u = ap[(size_t)s * 16];
          acc.x = fmaf(w, bf2f_lo(u.x), acc.x);
          acc.y = fmaf(w, bf2f_hi(u.x), acc.y);
          acc.z = fmaf(w, bf2f_lo(u.y), acc.z);
          acc.w = fmaf(w, bf2f_hi(u.y), acc.w);
        }
      }
      int rem = emax - full;
      if (rem > 0) {
        int idx = c0 + li;
        int er = (idx < ecnt) ? (int)csr[base + idx] : 0;
        for (int j = 0; j < rem; ++j) {
          unsigned r = (unsigned)__builtin_amdgcn_ds_bpermute(lsel | (j << 2), er);
          int s = (int)(r & 0x1FFFFu);
          float w = (float)(r >> 17) * (1.0f / 32768.0f);
          uint2 u = ap[(size_t)s * 16];
          acc.x = fmaf(w, bf2f_lo(u.x), acc.x);
          acc.y = fmaf(w, bf2f_hi(u.x), acc.y);
          acc.z = fmaf(w, bf2f_lo(u.y), acc.z);
          acc.w = fmaf(w, bf2f_hi(u.y), acc.w);
        }
      }
      acc.x = fmaxf(acc.x, 0.f);
      acc.y = fmaxf(acc.y, 0.f);
      acc.z = fmaxf(acc.z, 0.f);
      acc.w = fmaxf(acc.w, 0.f);
      if (write_h) ((float4*)h)[(size_t)v * 16 + li] = acc;
      uint2 p;
      p.x = f2bf(acc.x) | (f2bf(acc.y) << 16);
      p.y = f2bf(acc.z) | (f2bf(acc.w) << 16);
      ((uint2*)h_bf)[(size_t)v * 16 + li] = p;
    }
    gbar(bar, bid);
  }

  // ---- phase 11: head (mean-pool + lin1+relu + lin2), one wave per graph ----
  for (int g = gw; g < N_GRAPHS; g += NWAVE) {
    int lo = 0, hi = N_NODES;
    while (lo < hi) { int mid = (lo + hi) >> 1; if (batch[mid] < g) lo = mid + 1; else hi = mid; }
    int start = lo;
    hi = N_NODES;
    while (lo < hi) { int mid = (lo + hi) >> 1; if (batch[mid] < g + 1) lo = mid + 1; else hi = mid; }
    int end = lo;

    float sum = 0.f;
    for (int v = start; v < end; ++v) sum += h[(size_t)v * 64 + lane];
    float cntf = (float)(end - start);
    float gx = sum / fmaxf(cntf, 1.f);

    float acc = l1b[lane];
    for (int k = 0; k < 64; ++k) {
      float gxk = __shfl(gx, k);
      acc = fmaf(gxk, l1w[k * 64 + lane], acc);
    }
    float t = fmaxf(acc, 0.f);
    float p0 = t * l2w[lane * 3 + 0];
    float p1 = t * l2w[lane * 3 + 1];
    float p2 = t * l2w[lane * 3 + 2];
    for (int off = 32; off > 0; off >>= 1) {
      p0 += __shfl_down(p0, off);
      p1 += __shfl_down(p1, off);
      p2 += __shfl_down(p2, off);
    }
    if (lane == 0) {
      out[g * 3 + 0] = p0 + l2b[0];
      out[g * 3 + 1] = p1 + l2b[1];
      out[g * 3 + 2] = p2 + l2b[2];
    }
  }
}

// ---------------------------------------------------------------------------
extern "C" void kernel_launch(void* const* d_in, const int* in_sizes, int n_in,
                              void* d_out, int out_size, void* d_ws, size_t ws_size,
                              hipStream_t stream)
{
  (void)in_sizes; (void)n_in; (void)out_size; (void)ws_size;
  const float* x     = (const float*)d_in[0];
  const int*   ei    = (const int*)d_in[1];
  const float* ea    = (const float*)d_in[2];
  const int*   batch = (const int*)d_in[3];
  const float* emb_w = (const float*)d_in[4];
  const float* emb_b = (const float*)d_in[5];
  const float* cw1   = (const float*)d_in[6];
  const float* cb1   = (const float*)d_in[7];
  const float* cw2   = (const float*)d_in[8];
  const float* cw3   = (const float*)d_in[9];
  const float* cb3   = (const float*)d_in[10];
  const float* l1w   = (const float*)d_in[11];
  const float* l1b   = (const float*)d_in[12];
  const float* l2w   = (const float*)d_in[13];
  const float* l2b   = (const float*)d_in[14];
  float* out = (float*)d_out;

  char* wsb = (char*)d_ws;
  size_t off = 0;
  auto alloc = [&](size_t bytes) {
    char* p = wsb + off;
    off = (off + bytes + 255) & ~(size_t)255;
    return p;
  };
  float* h       = (float*)alloc(sizeof(float) * (size_t)N_NODES * 64);    // 25.6 MB
  unsigned short* h_bf = (unsigned short*)alloc(sizeof(short) * (size_t)N_NODES * 64);
  unsigned short* a_bf = (unsigned short*)alloc(sizeof(short) * (size_t)N_NODES * 64);
  unsigned short* cc_bf = (unsigned short*)alloc(sizeof(short) * (size_t)N_NODES * 64);
  unsigned* csr  = (unsigned*)alloc(sizeof(unsigned) * (size_t)NB * CAP);  // 14.0 MB slotted
  int*   row_off = (int*)alloc(sizeof(int) * N_NODES);
  unsigned short* deg16 = (unsigned short*)alloc(sizeof(short) * N_NODES);
  float* degw    = (float*)alloc(sizeof(float) * N_NODES);
  int*   gcur    = (int*)alloc(sizeof(int) * NB);
  unsigned* wswz = (unsigned*)alloc(sizeof(unsigned) * NLAYER * 6144);  // 96 KB
  int*   bar     = (int*)alloc(sizeof(int) * 34 * 32);
  // tmp_w (14.0 MB) + tmp_d (3.5 MB) alias h: h fp32 is only written by the
  // LAST agg phase, long after the sort phase consumed tmp (barriers order it).
  unsigned* tmp_w = (unsigned*)h;
  unsigned char* tmp_d = (unsigned char*)h + sizeof(unsigned) * (size_t)NB * CAP;

  zero_bar_kernel<<<1, 256, 0, stream>>>(bar);
  mega_kernel<<<NBLK, NTHREADS, 0, stream>>>(
      x, ei, ea, batch, emb_w, emb_b, cw1, cb1, cw2, cw3, cb3,
      l1w, l1b, l2w, l2b, out,
      h, h_bf, a_bf, cc_bf, csr, row_off, deg16, degw, gcur, wswz,
      tmp_w, tmp_d, bar);
}

// Round 10
// 520.188 us; speedup vs baseline: 6.0042x; 2.2785x over previous
//
#include <hip/hip_runtime.h>

#define N_NODES 100000
#define N_EDGES 3200000
#define N_GRAPHS 1000
#define NLAYER 4
#define NB 391           // coarse buckets: dst>>8, 391*256 = 100096 >= N_NODES
#define CAP 8960         // fixed slot cap per bucket (mean 8184, sd 90: +8.6 sigma)
#define EPB 4096         // edges per scatter chunk
#define NCHUNK 782       // 782*4096 >= N_EDGES

typedef __attribute__((ext_vector_type(8))) short bf16x8;
typedef __attribute__((ext_vector_type(4))) float f32x4;

static __device__ __forceinline__ unsigned f2bf(float f) {
  unsigned u = __float_as_uint(f);
  return (u + 0x7fffu + ((u >> 16) & 1u)) >> 16;
}
static __device__ __forceinline__ float bf2f_lo(unsigned u) {
  return __uint_as_float(u << 16);
}
static __device__ __forceinline__ float bf2f_hi(unsigned u) {
  return __uint_as_float(u & 0xffff0000u);
}

// ---------------------------------------------------------------------------
// Prologue: embed (all blocks) + gcur slot-base init (block 4) + weight
// swizzle (blocks 0..3). Fuses three independent round-6 kernels.
__global__ __launch_bounds__(256) void prologue_kernel(
    const float* __restrict__ x, const float* __restrict__ emb_w,
    const float* __restrict__ emb_b, unsigned short* __restrict__ h_bf,
    int* __restrict__ gcur,
    const float* __restrict__ cw1, const float* __restrict__ cw2,
    const float* __restrict__ cw3, unsigned* __restrict__ wswz)
{
  int tid = threadIdx.x;
  if (blockIdx.x == 4) {
    for (int i = tid; i < NB; i += 256) gcur[i] = i * CAP;
  }
  if (blockIdx.x < NLAYER) {  // weight swizzle, one layer per block
    int l = blockIdx.x;
    const float* w1 = cw1 + l * 4096;
    const float* w2 = cw2 + l * 4096;
    const float* w3 = cw3 + l * 4096;
    unsigned* outp = wswz + l * 6144;
    int n = tid & 63;
    int gofs = tid >> 6;
    for (int it = 0; it < 24; ++it) {
      int g = it * 4 + gofs;         // 0..95
      int m = g >> 5;                // 0..2 (0=W2, 1=W3, 2=W1)
      int k = (g & 31) * 2;          // even k
      const float* W = (m == 0) ? w2 : (m == 1) ? w3 : w1;
      unsigned lo = f2bf(W[k * 64 + n]);
      unsigned hi = f2bf(W[(k + 1) * 64 + n]);
      int c = k >> 5;
      int kk = k & 31;
      int ln = ((kk >> 3) << 4) | (n & 15);
      int j2 = (kk & 7) >> 1;
      int t4 = n >> 4;
      outp[(((m * 2 + c) * 4 + t4) << 8) | (ln << 2) | j2] = lo | (hi << 16);
    }
  }
  int t = blockIdx.x * 256 + tid;
  if (t >= N_NODES * 64) return;
  int c = t & 63, v = t >> 6;
  float4 xv = ((const float4*)x)[v];
  float acc = emb_b[c];
  acc = fmaf(xv.x, emb_w[0 * 64 + c], acc);
  acc = fmaf(xv.y, emb_w[1 * 64 + c], acc);
  acc = fmaf(xv.z, emb_w[2 * 64 + c], acc);
  acc = fmaf(xv.w, emb_w[3 * 64 + c], acc);
  h_bf[t] = (unsigned short)f2bf(acc);
}

// ---------------------------------------------------------------------------
// Staged scatter into fixed-capacity bucket slots (gcur pre-init to b*CAP —
// no global histogram/scan pass). Per block: LDS histogram -> ONE global
// atomicAdd range-claim per (block,bucket) -> 3-barrier shuffle scan -> LDS
// stage in bucket order -> coalesced flush (42 B avg runs). Record: final
// csr word (src | q15<<17, u32) + dst low byte (u8). Order within a bucket
// is arbitrary (only perturbs fp32 sum rounding).
__global__ __launch_bounds__(256) void bscatter_kernel(
    const int* __restrict__ ei, const float* __restrict__ ea,
    int* __restrict__ gcur, unsigned* __restrict__ tmp_w,
    unsigned char* __restrict__ tmp_d)
{
  __shared__ unsigned hist[NB];           // count -> local cursor
  __shared__ int dif[NB];                 // global_base - local_excl_base
  __shared__ unsigned stage_w[EPB];       // 16 KB
  __shared__ unsigned char stage_d[EPB];  // 4 KB
  __shared__ unsigned short bid[EPB];     // 8 KB
  __shared__ int wpart[4];
  int tid = threadIdx.x;
  int base = blockIdx.x * EPB;

  for (int i = tid; i < NB; i += 256) hist[i] = 0;
  __syncthreads();

  int dreg[16];
#pragma unroll
  for (int i = 0; i < 16; ++i) {
    int e = base + i * 256 + tid;
    dreg[i] = -1;
    if (e < N_EDGES) {
      int d = ei[N_EDGES + e];
      dreg[i] = d;
      atomicAdd(&hist[((unsigned)d) >> 8], 1u);
    }
  }
  __syncthreads();

  // exclusive scan over NB buckets (2 per thread) + global range claim
  int lane = tid & 63, w = tid >> 6;
  int b0i = tid * 2, b1i = tid * 2 + 1;
  int c0 = (b0i < NB) ? (int)hist[b0i] : 0;
  int c1 = (b1i < NB) ? (int)hist[b1i] : 0;
  int tsum = c0 + c1;
  int s = tsum;
#pragma unroll
  for (int off = 1; off < 64; off <<= 1) {
    int y = __shfl_up(s, off);
    if (lane >= off) s += y;
  }
  if (lane == 63) wpart[w] = s;
  __syncthreads();
  int wo = 0;
  for (int ww = 0; ww < w; ++ww) wo += wpart[ww];
  int excl = wo + (s - tsum);
  if (b0i < NB) {
    int gb = c0 ? atomicAdd(&gcur[b0i], c0) : 0;
    dif[b0i] = gb - excl;
    hist[b0i] = (unsigned)excl;  // local cursor
  }
  if (b1i < NB) {
    int gb = c1 ? atomicAdd(&gcur[b1i], c1) : 0;
    dif[b1i] = gb - (excl + c0);
    hist[b1i] = (unsigned)(excl + c0);
  }
  __syncthreads();

  // stage in bucket-sorted order
#pragma unroll
  for (int i = 0; i < 16; ++i) {
    int e = base + i * 256 + tid;
    int d = dreg[i];
    if (d >= 0) {
      unsigned bkt = ((unsigned)d) >> 8;
      unsigned lp = atomicAdd(&hist[bkt], 1u);
      unsigned q15 = (unsigned)(ea[e] * 32768.0f);  // ew in [0,1)
      stage_w[lp] = ((unsigned)ei[e]) | (q15 << 17);
      stage_d[lp] = (unsigned char)(d & 255);
      bid[lp] = (unsigned short)bkt;
    }
  }
  __syncthreads();

  // coalesced flush (slotted positions)
  int nE = min(EPB, N_EDGES - base);
  for (int i = tid; i < nE; i += 256) {
    int g = dif[bid[i]] + i;
    tmp_w[g] = stage_w[i];
    tmp_d[g] = stage_d[i];
  }
}

// ---------------------------------------------------------------------------
// One block per bucket: 256-bin LDS counting sort (u16 permutation) ->
// contiguous csr write into the bucket's slot; emits row_off (slot-global),
// deg16, degw (from q15 weights, exactly matching csr message weights).
__global__ __launch_bounds__(256) void bucket_sort_kernel(
    const int* __restrict__ gcur, const unsigned* __restrict__ tmp_w,
    const unsigned char* __restrict__ tmp_d,
    unsigned* __restrict__ csr, int* __restrict__ row_off,
    unsigned short* __restrict__ deg16, float* __restrict__ degw)
{
  int j = blockIdx.x;
  int b0 = j * CAP;
  int nE = min(gcur[j] - b0, CAP);
  __shared__ unsigned hist[256];
  __shared__ float dws[256];
  __shared__ unsigned cur[256];
  __shared__ int wpart[4];
  __shared__ unsigned short perm[CAP];  // 17.9 KB
  int t = threadIdx.x;
  hist[t] = 0;
  dws[t] = 0.f;
  __syncthreads();
  for (int i = t; i < nE; i += 256) {
    unsigned d = tmp_d[b0 + i];
    unsigned wrd = tmp_w[b0 + i];
    atomicAdd(&hist[d], 1u);
    atomicAdd(&dws[d], (float)(wrd >> 17) * (1.0f / 32768.0f));
  }
  __syncthreads();
  // shuffle exclusive scan of hist[256]
  int lane = t & 63, w = t >> 6;
  int v = (int)hist[t];
  int s = v;
#pragma unroll
  for (int off = 1; off < 64; off <<= 1) {
    int y = __shfl_up(s, off);
    if (lane >= off) s += y;
  }
  if (lane == 63) wpart[w] = s;
  __syncthreads();
  int wo = 0;
  for (int ww = 0; ww < w; ++ww) wo += wpart[ww];
  int excl = wo + s - v;
  cur[t] = (unsigned)excl;
  int vnode = (j << 8) + t;
  if (vnode < N_NODES) {
    row_off[vnode] = b0 + excl;
    deg16[vnode] = (unsigned short)v;
    degw[vnode] = dws[t];
  }
  __syncthreads();

  for (int i = t; i < nE; i += 256) {
    unsigned p = atomicAdd(&cur[tmp_d[b0 + i]], 1u);
    perm[p] = (unsigned short)i;
  }
  __syncthreads();
  for (int q = t; q < nE; q += 256)
    csr[b0 + q] = tmp_w[b0 + (int)perm[q]];
}

// ---------------------------------------------------------------------------
// MFMA matvec: one 16-node tile per wave.
//   a_bf  = bf16(h@W1 + b1)
//   cc_bf = bf16(b3 + h@W3 - deg_w*(h@W2))
__global__ __launch_bounds__(256) void matvec3_mfma_kernel(
    const unsigned short* __restrict__ h_bf,
    const unsigned* __restrict__ wz,   // this layer's 6144-word slice
    const float* __restrict__ b1, const float* __restrict__ b3,
    const float* __restrict__ degw,
    unsigned short* __restrict__ a_bf, unsigned short* __restrict__ cc_bf)
{
  int gw = (blockIdx.x * 256 + threadIdx.x) >> 6;  // global wave = tile index
  int lane = threadIdx.x & 63;
  int quad = lane >> 4;
  int col = lane & 15;
  int nb = gw * 16;
  if (nb >= N_NODES) return;  // wave-uniform exit

  int arow = nb + col;
  if (arow >= N_NODES) arow = N_NODES - 1;
  const bf16x8* ap = (const bf16x8*)(h_bf + (size_t)arow * 64 + quad * 8);
  bf16x8 af0 = ap[0];
  bf16x8 af1 = ap[4];

  float dwr[4];
#pragma unroll
  for (int r = 0; r < 4; ++r) {
    int row = nb + quad * 4 + r;
    dwr[r] = degw[row < N_NODES ? row : 0];
  }

#pragma unroll
  for (int t = 0; t < 4; ++t) {
    const bf16x8* b20 = (const bf16x8*)&wz[((0 * 4 + t) << 8) + lane * 4];
    const bf16x8* b21 = (const bf16x8*)&wz[((1 * 4 + t) << 8) + lane * 4];
    const bf16x8* b30 = (const bf16x8*)&wz[((2 * 4 + t) << 8) + lane * 4];
    const bf16x8* b31 = (const bf16x8*)&wz[((3 * 4 + t) << 8) + lane * 4];
    const bf16x8* b10 = (const bf16x8*)&wz[((4 * 4 + t) << 8) + lane * 4];
    const bf16x8* b11 = (const bf16x8*)&wz[((5 * 4 + t) << 8) + lane * 4];

    f32x4 z = {0.f, 0.f, 0.f, 0.f};
    f32x4 acc2 = __builtin_amdgcn_mfma_f32_16x16x32_bf16(af0, *b20, z, 0, 0, 0);
    acc2 = __builtin_amdgcn_mfma_f32_16x16x32_bf16(af1, *b21, acc2, 0, 0, 0);
    f32x4 cc;
#pragma unroll
    for (int r = 0; r < 4; ++r) cc[r] = -dwr[r] * acc2[r];
    cc = __builtin_amdgcn_mfma_f32_16x16x32_bf16(af0, *b30, cc, 0, 0, 0);
    cc = __builtin_amdgcn_mfma_f32_16x16x32_bf16(af1, *b31, cc, 0, 0, 0);
    float bb3 = b3[t * 16 + col];
#pragma unroll
    for (int r = 0; r < 4; ++r) {
      int row = nb + quad * 4 + r;
      if (row < N_NODES)
        cc_bf[(size_t)row * 64 + t * 16 + col] = (unsigned short)f2bf(cc[r] + bb3);
    }

    float bb1 = b1[t * 16 + col];
    f32x4 a1 = {bb1, bb1, bb1, bb1};
    a1 = __builtin_amdgcn_mfma_f32_16x16x32_bf16(af0, *b10, a1, 0, 0, 0);
    a1 = __builtin_amdgcn_mfma_f32_16x16x32_bf16(af1, *b11, a1, 0, 0, 0);
#pragma unroll
    for (int r = 0; r < 4; ++r) {
      int row = nb + quad * 4 + r;
      if (row < N_NODES)
        a_bf[(size_t)row * 64 + t * 16 + col] = (unsigned short)f2bf(a1[r]);
    }
  }
}

// ---------------------------------------------------------------------------
// h_new[v] = relu(cc[v] + sum_{e in CSR(v)} ew_e * a[src_e])
// 4 consecutive nodes/wave, 16 lanes per node; wave-max trip count.
// a/cc bf16; csr u32 (src 17b | q15 15b); degree from deg16 (slotted csr).
__global__ __launch_bounds__(256) void agg_kernel(
    const uint2* __restrict__ a2, const uint2* __restrict__ cc2,
    const int* __restrict__ row_off, const unsigned short* __restrict__ deg16,
    const unsigned* __restrict__ csr,
    float4* __restrict__ h4, unsigned short* __restrict__ h_bf, int write_h)
{
  int wave = (blockIdx.x * 256 + threadIdx.x) >> 6;
  int lane = threadIdx.x & 63;
  int sg = lane >> 4;
  int li = lane & 15;
  int lsel = (lane & 48) << 2;  // sg*64 : byte lane-address base for bpermute
  int v = wave * 4 + sg;
  bool valid = v < N_NODES;
  int vc = valid ? v : N_NODES - 1;
  int base = row_off[vc];
  int ecnt = valid ? (int)deg16[vc] : 0;
  int emax = ecnt;
  emax = max(emax, __shfl_xor(emax, 16));
  emax = max(emax, __shfl_xor(emax, 32));

  float4 acc = make_float4(0.f, 0.f, 0.f, 0.f);
  if (valid) {
    uint2 cu = cc2[(size_t)vc * 16 + li];
    acc.x = bf2f_lo(cu.x);
    acc.y = bf2f_hi(cu.x);
    acc.z = bf2f_lo(cu.y);
    acc.w = bf2f_hi(cu.y);
  }
  const uint2* ap = a2 + li;

  int full = emax & ~15;
  int c0 = 0;
  for (; c0 < full; c0 += 16) {
    int idx = c0 + li;
    int er = (idx < ecnt) ? (int)csr[base + idx] : 0;  // pad: src 0, w 0
#pragma unroll
    for (int j = 0; j < 16; ++j) {
      unsigned r = (unsigned)__builtin_amdgcn_ds_bpermute(lsel | (j << 2), er);
      int s = (int)(r & 0x1FFFFu);
      float w = (float)(r >> 17) * (1.0f / 32768.0f);
      uint2 u = ap[(size_t)s * 16];
      acc.x = fmaf(w, bf2f_lo(u.x), acc.x);
      acc.y = fmaf(w, bf2f_hi(u.x), acc.y);
      acc.z = fmaf(w, bf2f_lo(u.y), acc.z);
      acc.w = fmaf(w, bf2f_hi(u.y), acc.w);
    }
  }
  int rem = emax - full;
  if (rem > 0) {
    int idx = c0 + li;
    int er = (idx < ecnt) ? (int)csr[base + idx] : 0;
    for (int j = 0; j < rem; ++j) {
      unsigned r = (unsigned)__builtin_amdgcn_ds_bpermute(lsel | (j << 2), er);
      int s = (int)(r & 0x1FFFFu);
      float w = (float)(r >> 17) * (1.0f / 32768.0f);
      uint2 u = ap[(size_t)s * 16];
      acc.x = fmaf(w, bf2f_lo(u.x), acc.x);
      acc.y = fmaf(w, bf2f_hi(u.x), acc.y);
      acc.z = fmaf(w, bf2f_lo(u.y), acc.z);
      acc.w = fmaf(w, bf2f_hi(u.y), acc.w);
    }
  }
  if (valid) {
    acc.x = fmaxf(acc.x, 0.f);
    acc.y = fmaxf(acc.y, 0.f);
    acc.z = fmaxf(acc.z, 0.f);
    acc.w = fmaxf(acc.w, 0.f);
    if (write_h) h4[(size_t)v * 16 + li] = acc;
    uint2 p;
    p.x = f2bf(acc.x) | (f2bf(acc.y) << 16);
    p.y = f2bf(acc.z) | (f2bf(acc.w) << 16);
    ((uint2*)h_bf)[(size_t)v * 16 + li] = p;
  }
}

// ---------------------------------------------------------------------------
// fused mean-pool (sorted batch, binary search) + lin1+relu + lin2, wave/graph
__global__ __launch_bounds__(256) void head_kernel(
    const float* __restrict__ h, const int* __restrict__ batch,
    const float* __restrict__ l1w, const float* __restrict__ l1b,
    const float* __restrict__ l2w, const float* __restrict__ l2b,
    float* __restrict__ out)
{
  int g = (blockIdx.x * 256 + threadIdx.x) >> 6;
  int lane = threadIdx.x & 63;
  if (g >= N_GRAPHS) return;
  int lo = 0, hi = N_NODES;
  while (lo < hi) { int mid = (lo + hi) >> 1; if (batch[mid] < g) lo = mid + 1; else hi = mid; }
  int start = lo;
  hi = N_NODES;
  while (lo < hi) { int mid = (lo + hi) >> 1; if (batch[mid] < g + 1) lo = mid + 1; else hi = mid; }
  int end = lo;

  float sum = 0.f;
  for (int v = start; v < end; ++v) sum += h[(size_t)v * 64 + lane];
  float cntf = (float)(end - start);
  float gx = sum / fmaxf(cntf, 1.f);

  float acc = l1b[lane];
  for (int k = 0; k < 64; ++k) {
    float gxk = __shfl(gx, k);
    acc = fmaf(gxk, l1w[k * 64 + lane], acc);
  }
  float t = fmaxf(acc, 0.f);
  float p0 = t * l2w[lane * 3 + 0];
  float p1 = t * l2w[lane * 3 + 1];
  float p2 = t * l2w[lane * 3 + 2];
  for (int off = 32; off > 0; off >>= 1) {
    p0 += __shfl_down(p0, off);
    p1 += __shfl_down(p1, off);
    p2 += __shfl_down(p2, off);
  }
  if (lane == 0) {
    out[g * 3 + 0] = p0 + l2b[0];
    out[g * 3 + 1] = p1 + l2b[1];
    out[g * 3 + 2] = p2 + l2b[2];
  }
}

// ---------------------------------------------------------------------------
extern "C" void kernel_launch(void* const* d_in, const int* in_sizes, int n_in,
                              void* d_out, int out_size, void* d_ws, size_t ws_size,
                              hipStream_t stream)
{
  (void)in_sizes; (void)n_in; (void)out_size; (void)ws_size;
  const float* x     = (const float*)d_in[0];
  const int*   ei    = (const int*)d_in[1];
  const float* ea    = (const float*)d_in[2];
  const int*   batch = (const int*)d_in[3];
  const float* emb_w = (const float*)d_in[4];
  const float* emb_b = (const float*)d_in[5];
  const float* cw1   = (const float*)d_in[6];
  const float* cb1   = (const float*)d_in[7];
  const float* cw2   = (const float*)d_in[8];
  const float* cw3   = (const float*)d_in[9];
  const float* cb3   = (const float*)d_in[10];
  const float* l1w   = (const float*)d_in[11];
  const float* l1b   = (const float*)d_in[12];
  const float* l2w   = (const float*)d_in[13];
  const float* l2b   = (const float*)d_in[14];
  float* out = (float*)d_out;

  char* wsb = (char*)d_ws;
  size_t off = 0;
  auto alloc = [&](size_t bytes) {
    char* p = wsb + off;
    off = (off + bytes + 255) & ~(size_t)255;
    return p;
  };
  float* h       = (float*)alloc(sizeof(float) * (size_t)N_NODES * 64);    // 25.6 MB
  unsigned short* h_bf = (unsigned short*)alloc(sizeof(short) * (size_t)N_NODES * 64);
  unsigned short* a_bf = (unsigned short*)alloc(sizeof(short) * (size_t)N_NODES * 64);
  unsigned short* cc_bf = (unsigned short*)alloc(sizeof(short) * (size_t)N_NODES * 64);
  unsigned* csr  = (unsigned*)alloc(sizeof(unsigned) * (size_t)NB * CAP);  // 14.0 MB slotted
  int*   row_off = (int*)alloc(sizeof(int) * N_NODES);
  unsigned short* deg16 = (unsigned short*)alloc(sizeof(short) * N_NODES);
  float* degw    = (float*)alloc(sizeof(float) * N_NODES);
  int*   gcur    = (int*)alloc(sizeof(int) * NB);
  unsigned* wswz = (unsigned*)alloc(sizeof(unsigned) * NLAYER * 6144);  // 96 KB
  // tmp_w (14.0 MB) + tmp_d (3.5 MB) alias h: h fp32 is only written by the
  // LAST agg, long after bucket_sort consumed tmp.
  unsigned* tmp_w = (unsigned*)h;
  unsigned char* tmp_d = (unsigned char*)h + sizeof(unsigned) * (size_t)NB * CAP;

  prologue_kernel<<<(N_NODES * 64 + 255) / 256, 256, 0, stream>>>(
      x, emb_w, emb_b, h_bf, gcur, cw1, cw2, cw3, wswz);
  bscatter_kernel<<<NCHUNK, 256, 0, stream>>>(ei, ea, gcur, tmp_w, tmp_d);
  bucket_sort_kernel<<<NB, 256, 0, stream>>>(gcur, tmp_w, tmp_d, csr, row_off,
                                             deg16, degw);

  int agg_blocks = (N_NODES + 15) / 16;   // 4 nodes/wave, 4 waves/block
  int mv_blocks = (N_NODES / 16 + 3) / 4 + 1;
  for (int l = 0; l < NLAYER; ++l) {
    matvec3_mfma_kernel<<<mv_blocks, 256, 0, stream>>>(
        h_bf, wswz + l * 6144, cb1 + l * 64, cb3 + l * 64, degw, a_bf, cc_bf);
    agg_kernel<<<agg_blocks, 256, 0, stream>>>(
        (const uint2*)a_bf, (const uint2*)cc_bf, row_off, deg16, csr, (float4*)h,
        h_bf, (l == NLAYER - 1) ? 1 : 0);
  }

  head_kernel<<<(N_GRAPHS * 64 + 255) / 256, 256, 0, stream>>>(
      h, batch, l1w, l1b, l2w, l2b, out);
}

// Round 11
// 510.570 us; speedup vs baseline: 6.1174x; 1.0188x over previous
//
#include <hip/hip_runtime.h>

#define N_NODES 100000
#define N_EDGES 3200000
#define N_GRAPHS 1000
#define NLAYER 4
#define NB 391           // coarse buckets: dst>>8, 391*256 = 100096 >= N_NODES
#define CAP 8960         // fixed slot cap per bucket (mean 8184, sd 90: +8.6 sigma)
#define EPB 4096         // edges per scatter chunk
#define NCHUNK 782       // 782*4096 >= N_EDGES

typedef __attribute__((ext_vector_type(8))) short bf16x8;
typedef __attribute__((ext_vector_type(4))) float f32x4;

static __device__ __forceinline__ unsigned f2bf(float f) {
  unsigned u = __float_as_uint(f);
  return (u + 0x7fffu + ((u >> 16) & 1u)) >> 16;
}
static __device__ __forceinline__ float bf2f_lo(unsigned u) {
  return __uint_as_float(u << 16);
}
static __device__ __forceinline__ float bf2f_hi(unsigned u) {
  return __uint_as_float(u & 0xffff0000u);
}

// ---------------------------------------------------------------------------
// Prologue: embed (all blocks) + gcur slot-base init (block 4) + weight
// swizzle (blocks 0..3).
__global__ __launch_bounds__(256) void prologue_kernel(
    const float* __restrict__ x, const float* __restrict__ emb_w,
    const float* __restrict__ emb_b, unsigned short* __restrict__ h_bf,
    int* __restrict__ gcur,
    const float* __restrict__ cw1, const float* __restrict__ cw2,
    const float* __restrict__ cw3, unsigned* __restrict__ wswz)
{
  int tid = threadIdx.x;
  if (blockIdx.x == 4) {
    for (int i = tid; i < NB; i += 256) gcur[i] = i * CAP;
  }
  if (blockIdx.x < NLAYER) {  // weight swizzle, one layer per block
    int l = blockIdx.x;
    const float* w1 = cw1 + l * 4096;
    const float* w2 = cw2 + l * 4096;
    const float* w3 = cw3 + l * 4096;
    unsigned* outp = wswz + l * 6144;
    int n = tid & 63;
    int gofs = tid >> 6;
    for (int it = 0; it < 24; ++it) {
      int g = it * 4 + gofs;         // 0..95
      int m = g >> 5;                // 0..2 (0=W2, 1=W3, 2=W1)
      int k = (g & 31) * 2;          // even k
      const float* W = (m == 0) ? w2 : (m == 1) ? w3 : w1;
      unsigned lo = f2bf(W[k * 64 + n]);
      unsigned hi = f2bf(W[(k + 1) * 64 + n]);
      int c = k >> 5;
      int kk = k & 31;
      int ln = ((kk >> 3) << 4) | (n & 15);
      int j2 = (kk & 7) >> 1;
      int t4 = n >> 4;
      outp[(((m * 2 + c) * 4 + t4) << 8) | (ln << 2) | j2] = lo | (hi << 16);
    }
  }
  int t = blockIdx.x * 256 + tid;
  if (t >= N_NODES * 64) return;
  int c = t & 63, v = t >> 6;
  float4 xv = ((const float4*)x)[v];
  float acc = emb_b[c];
  acc = fmaf(xv.x, emb_w[0 * 64 + c], acc);
  acc = fmaf(xv.y, emb_w[1 * 64 + c], acc);
  acc = fmaf(xv.z, emb_w[2 * 64 + c], acc);
  acc = fmaf(xv.w, emb_w[3 * 64 + c], acc);
  h_bf[t] = (unsigned short)f2bf(acc);
}

// ---------------------------------------------------------------------------
// Staged scatter into fixed-capacity bucket slots. src+q15 record prefetched
// into VGPRs during the histogram pass (overlaps LDS atomics) so the
// post-claim staging pass is LDS-only (round-10: those loads serialized
// behind the barrier + global-atomic claim at 3 blocks/CU).
__global__ __launch_bounds__(256) void bscatter_kernel(
    const int* __restrict__ ei, const float* __restrict__ ea,
    int* __restrict__ gcur, unsigned* __restrict__ tmp_w,
    unsigned char* __restrict__ tmp_d)
{
  __shared__ unsigned hist[NB];           // count -> local cursor
  __shared__ int dif[NB];                 // global_base - local_excl_base
  __shared__ unsigned stage_w[EPB];       // 16 KB
  __shared__ unsigned char stage_d[EPB];  // 4 KB
  __shared__ unsigned short bid[EPB];     // 8 KB
  __shared__ int wpart[4];
  int tid = threadIdx.x;
  int base = blockIdx.x * EPB;

  for (int i = tid; i < NB; i += 256) hist[i] = 0;
  __syncthreads();

  int dreg[16];
  unsigned wreg[16];
#pragma unroll
  for (int i = 0; i < 16; ++i) {
    int e = base + i * 256 + tid;
    dreg[i] = -1;
    if (e < N_EDGES) {
      int d = ei[N_EDGES + e];
      dreg[i] = d;
      unsigned q15 = (unsigned)(ea[e] * 32768.0f);  // ew in [0,1)
      wreg[i] = ((unsigned)ei[e]) | (q15 << 17);
      atomicAdd(&hist[((unsigned)d) >> 8], 1u);
    }
  }
  __syncthreads();

  // exclusive scan over NB buckets (2 per thread) + global range claim
  int lane = tid & 63, w = tid >> 6;
  int b0i = tid * 2, b1i = tid * 2 + 1;
  int c0 = (b0i < NB) ? (int)hist[b0i] : 0;
  int c1 = (b1i < NB) ? (int)hist[b1i] : 0;
  int tsum = c0 + c1;
  int s = tsum;
#pragma unroll
  for (int off = 1; off < 64; off <<= 1) {
    int y = __shfl_up(s, off);
    if (lane >= off) s += y;
  }
  if (lane == 63) wpart[w] = s;
  __syncthreads();
  int wo = 0;
  for (int ww = 0; ww < w; ++ww) wo += wpart[ww];
  int excl = wo + (s - tsum);
  if (b0i < NB) {
    int gb = c0 ? atomicAdd(&gcur[b0i], c0) : 0;
    dif[b0i] = gb - excl;
    hist[b0i] = (unsigned)excl;  // local cursor
  }
  if (b1i < NB) {
    int gb = c1 ? atomicAdd(&gcur[b1i], c1) : 0;
    dif[b1i] = gb - (excl + c0);
    hist[b1i] = (unsigned)(excl + c0);
  }
  __syncthreads();

  // stage in bucket-sorted order (registers only — no global loads)
#pragma unroll
  for (int i = 0; i < 16; ++i) {
    int d = dreg[i];
    if (d >= 0) {
      unsigned bkt = ((unsigned)d) >> 8;
      unsigned lp = atomicAdd(&hist[bkt], 1u);
      stage_w[lp] = wreg[i];
      stage_d[lp] = (unsigned char)(d & 255);
      bid[lp] = (unsigned short)bkt;
    }
  }
  __syncthreads();

  // coalesced flush (slotted positions)
  int nE = min(EPB, N_EDGES - base);
  for (int i = tid; i < nE; i += 256) {
    int g = dif[bid[i]] + i;
    tmp_w[g] = stage_w[i];
    tmp_d[g] = stage_d[i];
  }
}

// ---------------------------------------------------------------------------
// One block per bucket: 256-bin LDS counting sort (u16 permutation) ->
// contiguous csr write into the bucket's slot; emits row_off (slot-global),
// deg16, degw (from q15 weights, exactly matching csr message weights).
__global__ __launch_bounds__(256) void bucket_sort_kernel(
    const int* __restrict__ gcur, const unsigned* __restrict__ tmp_w,
    const unsigned char* __restrict__ tmp_d,
    unsigned* __restrict__ csr, int* __restrict__ row_off,
    unsigned short* __restrict__ deg16, float* __restrict__ degw)
{
  int j = blockIdx.x;
  int b0 = j * CAP;
  int nE = min(gcur[j] - b0, CAP);
  __shared__ unsigned hist[256];
  __shared__ float dws[256];
  __shared__ unsigned cur[256];
  __shared__ int wpart[4];
  __shared__ unsigned short perm[CAP];  // 17.9 KB
  int t = threadIdx.x;
  hist[t] = 0;
  dws[t] = 0.f;
  __syncthreads();
  for (int i = t; i < nE; i += 256) {
    unsigned d = tmp_d[b0 + i];
    unsigned wrd = tmp_w[b0 + i];
    atomicAdd(&hist[d], 1u);
    atomicAdd(&dws[d], (float)(wrd >> 17) * (1.0f / 32768.0f));
  }
  __syncthreads();
  // shuffle exclusive scan of hist[256]
  int lane = t & 63, w = t >> 6;
  int v = (int)hist[t];
  int s = v;
#pragma unroll
  for (int off = 1; off < 64; off <<= 1) {
    int y = __shfl_up(s, off);
    if (lane >= off) s += y;
  }
  if (lane == 63) wpart[w] = s;
  __syncthreads();
  int wo = 0;
  for (int ww = 0; ww < w; ++ww) wo += wpart[ww];
  int excl = wo + s - v;
  cur[t] = (unsigned)excl;
  int vnode = (j << 8) + t;
  if (vnode < N_NODES) {
    row_off[vnode] = b0 + excl;
    deg16[vnode] = (unsigned short)v;
    degw[vnode] = dws[t];
  }
  __syncthreads();

  for (int i = t; i < nE; i += 256) {
    unsigned p = atomicAdd(&cur[tmp_d[b0 + i]], 1u);
    perm[p] = (unsigned short)i;
  }
  __syncthreads();
  for (int q = t; q < nE; q += 256)
    csr[b0 + q] = tmp_w[b0 + (int)perm[q]];
}

// ---------------------------------------------------------------------------
// MFMA matvec: one 16-node tile per wave.
//   a_bf  = bf16(h@W1 + b1)
//   cc_bf = bf16(b3 + h@W3 - deg_w*(h@W2))
__global__ __launch_bounds__(256) void matvec3_mfma_kernel(
    const unsigned short* __restrict__ h_bf,
    const unsigned* __restrict__ wz,   // this layer's 6144-word slice
    const float* __restrict__ b1, const float* __restrict__ b3,
    const float* __restrict__ degw,
    unsigned short* __restrict__ a_bf, unsigned short* __restrict__ cc_bf)
{
  int gw = (blockIdx.x * 256 + threadIdx.x) >> 6;  // global wave = tile index
  int lane = threadIdx.x & 63;
  int quad = lane >> 4;
  int col = lane & 15;
  int nb = gw * 16;
  if (nb >= N_NODES) return;  // wave-uniform exit

  int arow = nb + col;
  if (arow >= N_NODES) arow = N_NODES - 1;
  const bf16x8* ap = (const bf16x8*)(h_bf + (size_t)arow * 64 + quad * 8);
  bf16x8 af0 = ap[0];
  bf16x8 af1 = ap[4];

  float dwr[4];
#pragma unroll
  for (int r = 0; r < 4; ++r) {
    int row = nb + quad * 4 + r;
    dwr[r] = degw[row < N_NODES ? row : 0];
  }

#pragma unroll
  for (int t = 0; t < 4; ++t) {
    const bf16x8* b20 = (const bf16x8*)&wz[((0 * 4 + t) << 8) + lane * 4];
    const bf16x8* b21 = (const bf16x8*)&wz[((1 * 4 + t) << 8) + lane * 4];
    const bf16x8* b30 = (const bf16x8*)&wz[((2 * 4 + t) << 8) + lane * 4];
    const bf16x8* b31 = (const bf16x8*)&wz[((3 * 4 + t) << 8) + lane * 4];
    const bf16x8* b10 = (const bf16x8*)&wz[((4 * 4 + t) << 8) + lane * 4];
    const bf16x8* b11 = (const bf16x8*)&wz[((5 * 4 + t) << 8) + lane * 4];

    f32x4 z = {0.f, 0.f, 0.f, 0.f};
    f32x4 acc2 = __builtin_amdgcn_mfma_f32_16x16x32_bf16(af0, *b20, z, 0, 0, 0);
    acc2 = __builtin_amdgcn_mfma_f32_16x16x32_bf16(af1, *b21, acc2, 0, 0, 0);
    f32x4 cc;
#pragma unroll
    for (int r = 0; r < 4; ++r) cc[r] = -dwr[r] * acc2[r];
    cc = __builtin_amdgcn_mfma_f32_16x16x32_bf16(af0, *b30, cc, 0, 0, 0);
    cc = __builtin_amdgcn_mfma_f32_16x16x32_bf16(af1, *b31, cc, 0, 0, 0);
    float bb3 = b3[t * 16 + col];
#pragma unroll
    for (int r = 0; r < 4; ++r) {
      int row = nb + quad * 4 + r;
      if (row < N_NODES)
        cc_bf[(size_t)row * 64 + t * 16 + col] = (unsigned short)f2bf(cc[r] + bb3);
    }

    float bb1 = b1[t * 16 + col];
    f32x4 a1 = {bb1, bb1, bb1, bb1};
    a1 = __builtin_amdgcn_mfma_f32_16x16x32_bf16(af0, *b10, a1, 0, 0, 0);
    a1 = __builtin_amdgcn_mfma_f32_16x16x32_bf16(af1, *b11, a1, 0, 0, 0);
#pragma unroll
    for (int r = 0; r < 4; ++r) {
      int row = nb + quad * 4 + r;
      if (row < N_NODES)
        a_bf[(size_t)row * 64 + t * 16 + col] = (unsigned short)f2bf(a1[r]);
    }
  }
}

// ---------------------------------------------------------------------------
// h_new[v] = relu(cc[v] + sum_{e in CSR(v)} ew_e * a[src_e])
// 4 consecutive nodes/wave, 16 lanes per node; wave-max trip count.
// Inner loop restructured into 8-wide prefetch batches: 8 bpermutes ->
// 8 independent gathers in flight -> 32 fmas. (Round-10: 36 VGPR compile
// left only ~2-3 gathers outstanding; latency-bound.)
__global__ __launch_bounds__(256) void agg_kernel(
    const uint2* __restrict__ a2, const uint2* __restrict__ cc2,
    const int* __restrict__ row_off, const unsigned short* __restrict__ deg16,
    const unsigned* __restrict__ csr,
    float4* __restrict__ h4, unsigned short* __restrict__ h_bf, int write_h)
{
  int wave = (blockIdx.x * 256 + threadIdx.x) >> 6;
  int lane = threadIdx.x & 63;
  int sg = lane >> 4;
  int li = lane & 15;
  int lsel = (lane & 48) << 2;  // sg*64 : byte lane-address base for bpermute
  int v = wave * 4 + sg;
  bool valid = v < N_NODES;
  int vc = valid ? v : N_NODES - 1;
  int base = row_off[vc];
  int ecnt = valid ? (int)deg16[vc] : 0;
  int emax = ecnt;
  emax = max(emax, __shfl_xor(emax, 16));
  emax = max(emax, __shfl_xor(emax, 32));

  float4 acc = make_float4(0.f, 0.f, 0.f, 0.f);
  if (valid) {
    uint2 cu = cc2[(size_t)vc * 16 + li];
    acc.x = bf2f_lo(cu.x);
    acc.y = bf2f_hi(cu.x);
    acc.z = bf2f_lo(cu.y);
    acc.w = bf2f_hi(cu.y);
  }
  const uint2* ap = a2 + li;

  int full = emax & ~15;
  int c0 = 0;
  for (; c0 < full; c0 += 16) {
    int idx = c0 + li;
    int er = (idx < ecnt) ? (int)csr[base + idx] : 0;  // pad: src 0, w 0
#pragma unroll
    for (int jb = 0; jb < 2; ++jb) {
      unsigned rec[8];
#pragma unroll
      for (int j = 0; j < 8; ++j)
        rec[j] = (unsigned)__builtin_amdgcn_ds_bpermute(
            lsel | ((jb * 8 + j) << 2), er);
      uint2 u[8];
#pragma unroll
      for (int j = 0; j < 8; ++j)
        u[j] = ap[(size_t)(rec[j] & 0x1FFFFu) * 16];
#pragma unroll
      for (int j = 0; j < 8; ++j) {
        float w = (float)(rec[j] >> 17) * (1.0f / 32768.0f);
        acc.x = fmaf(w, bf2f_lo(u[j].x), acc.x);
        acc.y = fmaf(w, bf2f_hi(u[j].x), acc.y);
        acc.z = fmaf(w, bf2f_lo(u[j].y), acc.z);
        acc.w = fmaf(w, bf2f_hi(u[j].y), acc.w);
      }
    }
  }
  int rem = emax - full;
  if (rem > 0) {
    int idx = c0 + li;
    int er = (idx < ecnt) ? (int)csr[base + idx] : 0;
    for (int j = 0; j < rem; ++j) {
      unsigned r = (unsigned)__builtin_amdgcn_ds_bpermute(lsel | (j << 2), er);
      int s = (int)(r & 0x1FFFFu);
      float w = (float)(r >> 17) * (1.0f / 32768.0f);
      uint2 u = ap[(size_t)s * 16];
      acc.x = fmaf(w, bf2f_lo(u.x), acc.x);
      acc.y = fmaf(w, bf2f_hi(u.x), acc.y);
      acc.z = fmaf(w, bf2f_lo(u.y), acc.z);
      acc.w = fmaf(w, bf2f_hi(u.y), acc.w);
    }
  }
  if (valid) {
    acc.x = fmaxf(acc.x, 0.f);
    acc.y = fmaxf(acc.y, 0.f);
    acc.z = fmaxf(acc.z, 0.f);
    acc.w = fmaxf(acc.w, 0.f);
    if (write_h) h4[(size_t)v * 16 + li] = acc;
    uint2 p;
    p.x = f2bf(acc.x) | (f2bf(acc.y) << 16);
    p.y = f2bf(acc.z) | (f2bf(acc.w) << 16);
    ((uint2*)h_bf)[(size_t)v * 16 + li] = p;
  }
}

// ---------------------------------------------------------------------------
// fused mean-pool (sorted batch, binary search) + lin1+relu + lin2, wave/graph
__global__ __launch_bounds__(256) void head_kernel(
    const float* __restrict__ h, const int* __restrict__ batch,
    const float* __restrict__ l1w, const float* __restrict__ l1b,
    const float* __restrict__ l2w, const float* __restrict__ l2b,
    float* __restrict__ out)
{
  int g = (blockIdx.x * 256 + threadIdx.x) >> 6;
  int lane = threadIdx.x & 63;
  if (g >= N_GRAPHS) return;
  int lo = 0, hi = N_NODES;
  while (lo < hi) { int mid = (lo + hi) >> 1; if (batch[mid] < g) lo = mid + 1; else hi = mid; }
  int start = lo;
  hi = N_NODES;
  while (lo < hi) { int mid = (lo + hi) >> 1; if (batch[mid] < g + 1) lo = mid + 1; else hi = mid; }
  int end = lo;

  float sum = 0.f;
  for (int v = start; v < end; ++v) sum += h[(size_t)v * 64 + lane];
  float cntf = (float)(end - start);
  float gx = sum / fmaxf(cntf, 1.f);

  float acc = l1b[lane];
  for (int k = 0; k < 64; ++k) {
    float gxk = __shfl(gx, k);
    acc = fmaf(gxk, l1w[k * 64 + lane], acc);
  }
  float t = fmaxf(acc, 0.f);
  float p0 = t * l2w[lane * 3 + 0];
  float p1 = t * l2w[lane * 3 + 1];
  float p2 = t * l2w[lane * 3 + 2];
  for (int off = 32; off > 0; off >>= 1) {
    p0 += __shfl_down(p0, off);
    p1 += __shfl_down(p1, off);
    p2 += __shfl_down(p2, off);
  }
  if (lane == 0) {
    out[g * 3 + 0] = p0 + l2b[0];
    out[g * 3 + 1] = p1 + l2b[1];
    out[g * 3 + 2] = p2 + l2b[2];
  }
}

// ---------------------------------------------------------------------------
extern "C" void kernel_launch(void* const* d_in, const int* in_sizes, int n_in,
                              void* d_out, int out_size, void* d_ws, size_t ws_size,
                              hipStream_t stream)
{
  (void)in_sizes; (void)n_in; (void)out_size; (void)ws_size;
  const float* x     = (const float*)d_in[0];
  const int*   ei    = (const int*)d_in[1];
  const float* ea    = (const float*)d_in[2];
  const int*   batch = (const int*)d_in[3];
  const float* emb_w = (const float*)d_in[4];
  const float* emb_b = (const float*)d_in[5];
  const float* cw1   = (const float*)d_in[6];
  const float* cb1   = (const float*)d_in[7];
  const float* cw2   = (const float*)d_in[8];
  const float* cw3   = (const float*)d_in[9];
  const float* cb3   = (const float*)d_in[10];
  const float* l1w   = (const float*)d_in[11];
  const float* l1b   = (const float*)d_in[12];
  const float* l2w   = (const float*)d_in[13];
  const float* l2b   = (const float*)d_in[14];
  float* out = (float*)d_out;

  char* wsb = (char*)d_ws;
  size_t off = 0;
  auto alloc = [&](size_t bytes) {
    char* p = wsb + off;
    off = (off + bytes + 255) & ~(size_t)255;
    return p;
  };
  float* h       = (float*)alloc(sizeof(float) * (size_t)N_NODES * 64);    // 25.6 MB
  unsigned short* h_bf = (unsigned short*)alloc(sizeof(short) * (size_t)N_NODES * 64);
  unsigned short* a_bf = (unsigned short*)alloc(sizeof(short) * (size_t)N_NODES * 64);
  unsigned short* cc_bf = (unsigned short*)alloc(sizeof(short) * (size_t)N_NODES * 64);
  unsigned* csr  = (unsigned*)alloc(sizeof(unsigned) * (size_t)NB * CAP);  // 14.0 MB slotted
  int*   row_off = (int*)alloc(sizeof(int) * N_NODES);
  unsigned short* deg16 = (unsigned short*)alloc(sizeof(short) * N_NODES);
  float* degw    = (float*)alloc(sizeof(float) * N_NODES);
  int*   gcur    = (int*)alloc(sizeof(int) * NB);
  unsigned* wswz = (unsigned*)alloc(sizeof(unsigned) * NLAYER * 6144);  // 96 KB
  // tmp_w (14.0 MB) + tmp_d (3.5 MB) alias h: h fp32 is only written by the
  // LAST agg, long after bucket_sort consumed tmp.
  unsigned* tmp_w = (unsigned*)h;
  unsigned char* tmp_d = (unsigned char*)h + sizeof(unsigned) * (size_t)NB * CAP;

  prologue_kernel<<<(N_NODES * 64 + 255) / 256, 256, 0, stream>>>(
      x, emb_w, emb_b, h_bf, gcur, cw1, cw2, cw3, wswz);
  bscatter_kernel<<<NCHUNK, 256, 0, stream>>>(ei, ea, gcur, tmp_w, tmp_d);
  bucket_sort_kernel<<<NB, 256, 0, stream>>>(gcur, tmp_w, tmp_d, csr, row_off,
                                             deg16, degw);

  int agg_blocks = (N_NODES + 15) / 16;   // 4 nodes/wave, 4 waves/block
  int mv_blocks = (N_NODES / 16 + 3) / 4 + 1;
  for (int l = 0; l < NLAYER; ++l) {
    matvec3_mfma_kernel<<<mv_blocks, 256, 0, stream>>>(
        h_bf, wswz + l * 6144, cb1 + l * 64, cb3 + l * 64, degw, a_bf, cc_bf);
    agg_kernel<<<agg_blocks, 256, 0, stream>>>(
        (const uint2*)a_bf, (const uint2*)cc_bf, row_off, deg16, csr, (float4*)h,
        h_bf, (l == NLAYER - 1) ? 1 : 0);
  }

  head_kernel<<<(N_GRAPHS * 64 + 255) / 256, 256, 0, stream>>>(
      h, batch, l1w, l1b, l2w, l2b, out);
}